// Round 4
// baseline (87.884 us; speedup 1.0000x reference)
//
#include <hip/hip_runtime.h>
#include <math.h>

#define SLEN 53
#define NPIX 2809
#define NPARAM 12
#define BLK 256
#define TPB 4           // tiles per block
#define NSLOT 11        // ceil(2809/256)
#define KC 1.019230769230769231f   // 53/52

// atan, full range: reciprocal reduction to [0,1] + 6-term minimax poly in x^2.
__device__ __forceinline__ float fast_atan(float u) {
    float t = __builtin_fabsf(u);
    float rin = __builtin_amdgcn_rcpf(t);
    bool big = t > 1.0f;
    float w = big ? rin : t;                 // [0,1]
    float z = w * w;
    float p = -0.01172120f;
    p = __builtin_fmaf(p, z,  0.05265332f);
    p = __builtin_fmaf(p, z, -0.11643287f);
    p = __builtin_fmaf(p, z,  0.19354346f);
    p = __builtin_fmaf(p, z, -0.33262347f);
    p = __builtin_fmaf(p, z,  0.99997726f);
    float r = w * p;
    r = big ? 1.57079632679489662f - r : r;
    return __builtin_copysignf(r, u);
}

// atanh(v) = 0.5*ln2*log2((1+v)*rcp(1-v)); |v| <= sqrt(1-q^2) <= 0.995.
__device__ __forceinline__ float fast_atanh(float v) {
    float a = __builtin_fabsf(v);
    float t = (1.0f + a) * __builtin_amdgcn_rcpf(1.0f - a);
    float r = 0.34657359027997264f * __builtin_amdgcn_logf(t);
    return __builtin_copysignf(r, v);
}

// 4 tiles per block: pixel decode shared across tiles, 4 independent
// per-pixel chains for ILP, per-block prep amortized 4x, grid 4096->1024.
__global__ __launch_bounds__(BLK) void lgtd_kernel(
    const float* __restrict__ lens_params,
    const float* __restrict__ bools,
    float* __restrict__ out, int n_tiles)
{
    __shared__ float Etab[TPB][SLEN];
    const int base = blockIdx.x * TPB;
    const int tid = threadIdx.x;

    float blv[TPB];
    bool  val[TPB];
    bool  any = false;
    #pragma unroll
    for (int t = 0; t < TPB; ++t) {
        val[t] = (base + t < n_tiles);
        blv[t] = val[t] ? bools[base + t] : 0.0f;   // uniform -> s_load
        any = any || (blv[t] != 0.0f);
    }
    if (!any) {                                     // all-zero group (~0.8%)
        #pragma unroll
        for (int t = 0; t < TPB; ++t) {
            if (!val[t]) continue;
            float* outp = out + (size_t)(base + t) * NPIX;
            #pragma unroll 1
            for (int s = 0; s < NSLOT; ++s)
                outp[min(s * BLK + tid, NPIX - 1)] = 0.0f;
        }
        return;                                     // whole block exits before barrier
    }

    // ---- per-tile params, 4 independent prep chains (block-uniform) ----
    float cospv[TPB], sinpv[TPB], qv[TPB], qinvv[TPB], safev[TPB],
          bosv[TPB], cxv[TPB], cyv[TPB], bv[TPB], nh2v[TPB], sAv[TPB];
    bool  mbv[TPB];
    #pragma unroll
    for (int t = 0; t < TPB; ++t) {
        if (blv[t] == 0.0f) {   // benign placeholders, never used in compute
            cospv[t]=1.0f; sinpv[t]=0.0f; qv[t]=1.0f; qinvv[t]=1.0f;
            safev[t]=1.0f; bosv[t]=0.0f; cxv[t]=0.0f; cyv[t]=0.0f;
            bv[t]=0.0f; nh2v[t]=0.0f; sAv[t]=0.0f; mbv[t]=true;
            continue;
        }
        const float* p = lens_params + (size_t)(base + t) * NPARAM;
        const float flux = __builtin_fmaf(p[0], 1000.0f, 100.0f);
        const float sg   = __builtin_fmaf(p[3], 3.0f, 1.0f);
        const float s2   = sg * sg;
        const float rs2  = __builtin_amdgcn_rcpf(s2);
        const float A    = flux * 0.15915494309189533577f * rs2;  // flux/(2*pi*s2)
        nh2v[t] = -0.72134752044448170368f * rs2;                 // -0.5*log2(e)/s2
        bv[t] = p[7]; cxv[t] = p[8]; cyv[t] = p[9];
        const float e1 = p[10], e2 = p[11];
        const float rell = __builtin_amdgcn_rsqf(__builtin_fmaf(e1, e1, e2 * e2));
        const float cosp = e1 * rell;              // cos(atan(e2/e1)), e1>0
        const float sinp = e2 * rell;
        cospv[t] = cosp; sinpv[t] = sinp;
        const float ell  = __builtin_fmaf(e1, cosp, e2 * sinp);   // sqrt(e1^2+e2^2)
        const float q    = (1.0f - ell) * __builtin_amdgcn_rcpf(1.0f + ell);
        qv[t] = q;
        const float qinv = __builtin_amdgcn_rcpf(q);
        qinvv[t] = qinv;
        const float qf   = __builtin_amdgcn_sqrtf(qinv - q);
        const float safe = fmaxf(qf, 0.001f);
        safev[t] = safe;
        bosv[t]  = bv[t] * __builtin_amdgcn_rcpf(safe);
        mbv[t]   = (qf >= 0.001f);                 // always true for this data
        sAv[t]   = __builtin_amdgcn_sqrtf(A * blv[t]);
    }

    // ---- per-tile Gaussian corner tables: E[k]=sqrt(A*bl)*exp2(nh2*(k-26)^2)
    if (tid < SLEN) {
        const float d  = (float)tid - 26.0f;
        const float d2 = d * d;
        #pragma unroll
        for (int t = 0; t < TPB; ++t)              // static t index (no scratch)
            Etab[t][tid] = sAv[t] * __builtin_amdgcn_exp2f(nh2v[t] * d2);
    }
    __syncthreads();

    #pragma unroll 1
    for (int s = 0; s < NSLOT; ++s) {
        const int idx = min(s * BLK + tid, NPIX - 1);   // tail: redundant same-value store
        const unsigned i = ((unsigned)idx * 39569u) >> 21;   // idx/53 exact
        const int j = idx - (int)i * 53;
        const float xc = __builtin_fmaf((float)j, KC, -27.0f);
        const float yc = __builtin_fmaf((float)i, KC, -27.0f);
        const float xs26 = xc + 26.0f;
        const float ys26 = yc + 26.0f;

        #pragma unroll
        for (int t = 0; t < TPB; ++t) {
            if (!val[t]) continue;                  // uniform branch
            float* outp = out + (size_t)(base + t) * NPIX + idx;
            if (blv[t] == 0.0f) { *outp = 0.0f; continue; }  // uniform per tile

            // ---- SIE deflection ----
            const float dx = xc - cxv[t], dy = yc - cyv[t];
            const float xsie = __builtin_fmaf(dx, cospv[t], dy * sinpv[t]);
            const float ysie = __builtin_fmaf(dy, cospv[t], -dx * sinpv[t]);
            const float arg  = __builtin_fmaf(qv[t] * xsie, xsie,
                               __builtin_fmaf(qinvv[t] * ysie, ysie, 1e-12f));
            const float rcp_r = __builtin_amdgcn_rsqf(arg);   // 1/r_ell
            float xtg, ytg;
            if (mbv[t]) {
                const float srr = safev[t] * rcp_r;
                xtg = bosv[t] * fast_atan(srr * xsie);
                ytg = bosv[t] * fast_atanh(srr * ysie);
            } else {
                const float brr = bv[t] * rcp_r;
                xtg = brr * xsie;
                ytg = brr * ysie;
            }
            const float xg = __builtin_fmaf(xtg, cospv[t], -ytg * sinpv[t]);
            const float yg = __builtin_fmaf(ytg, cospv[t],  xtg * sinpv[t]);

            // ---- bilinear sample coords ----
            const float xs = xs26 - xg;
            const float ys = ys26 - yg;
            const float fx = __builtin_floorf(xs);
            const float fy = __builtin_floorf(ys);
            const float x0f = fminf(fmaxf(fx,        0.0f), 52.0f);  // v_med3
            const float x1f = fminf(fmaxf(fx + 1.0f, 0.0f), 52.0f);
            const float y0f = fminf(fmaxf(fy,        0.0f), 52.0f);
            const float y1f = fminf(fmaxf(fy + 1.0f, 0.0f), 52.0f);

            // ---- corner Gaussian values from the per-tile LDS table ----
            const float Ex0 = Etab[t][(int)x0f];
            const float Ex1 = Etab[t][(int)x1f];
            const float Ey0 = Etab[t][(int)y0f];
            const float Ey1 = Etab[t][(int)y1f];

            // separable bilinear; sqrt(A*bl) folded into table
            const float Fx = __builtin_fmaf(x1f - xs, Ex0, (xs - x0f) * Ex1);
            const float Fy = __builtin_fmaf(y1f - ys, Ey0, (ys - y0f) * Ey1);
            *outp = Fx * Fy;
        }
    }
}

extern "C" void kernel_launch(void* const* d_in, const int* in_sizes, int n_in,
                              void* d_out, int out_size, void* d_ws, size_t ws_size,
                              hipStream_t stream) {
    const float* lens  = (const float*)d_in[0];  // (N, 1, 12) fp32
    const float* bools = (const float*)d_in[1];  // (N, 1, 1)  fp32
    float* out = (float*)d_out;                  // (N, 1, 1, 53, 53) fp32
    const int n_tiles = in_sizes[1];
    const int ngrp = (n_tiles + TPB - 1) / TPB;
    lgtd_kernel<<<ngrp, BLK, 0, stream>>>(lens, bools, out, n_tiles);
}

// Round 5
// 81.991 us; speedup vs baseline: 1.0719x; 1.0719x over previous
//
#include <hip/hip_runtime.h>
#include <math.h>

#define SLEN 53
#define NPIX 2809
#define NPARAM 12
#define BLK 256
#define NSLOT 11       // ceil(2809/256)
#define KC 1.019230769230769231f   // 53/52

// atan, full range: reciprocal reduction to [0,1] + 6-term minimax poly in x^2.
// Max abs err ~1e-5 rad -> value err <= ~0.1 (threshold 2.94).
__device__ __forceinline__ float fast_atan(float u) {
    float t = __builtin_fabsf(u);
    float rin = __builtin_amdgcn_rcpf(t);
    bool big = t > 1.0f;
    float w = big ? rin : t;                 // [0,1]
    float z = w * w;
    float p = -0.01172120f;
    p = __builtin_fmaf(p, z,  0.05265332f);
    p = __builtin_fmaf(p, z, -0.11643287f);
    p = __builtin_fmaf(p, z,  0.19354346f);
    p = __builtin_fmaf(p, z, -0.33262347f);
    p = __builtin_fmaf(p, z,  0.99997726f);
    float r = w * p;
    r = big ? 1.57079632679489662f - r : r;
    return __builtin_copysignf(r, u);
}

// atanh(v) = 0.5*ln2*log2((1+v)*rcp(1-v)); |v| <= sqrt(1-q^2) <= 0.995.
__device__ __forceinline__ float fast_atanh(float v) {
    float a = __builtin_fabsf(v);
    float t = (1.0f + a) * __builtin_amdgcn_rcpf(1.0f - a);
    float r = 0.34657359027997264f * __builtin_amdgcn_logf(t);
    return __builtin_copysignf(r, v);
}

// Best-verified structure (R2, 82.7us) + micro-trim: the +26 shift is folded
// into the pixel decode (xc26 = j*KC - 1) and the tile center (cx26 = cx+26),
// removing 4 VALU ops/px. Per-tile LDS table of the 53 Gaussian corner values
// E[k] = sqrt(A*bl)*exp2(nh2*(k-26)^2); Fx*Fy product restores A*bl.
__global__ __launch_bounds__(BLK) void lgtd_kernel(
    const float* __restrict__ lens_params,
    const float* __restrict__ bools,
    float* __restrict__ out)
{
    __shared__ float Etab[SLEN];
    const int tile = blockIdx.x;
    float* outp = out + (size_t)tile * NPIX;
    const int tid = threadIdx.x;

    const float bl = bools[tile];              // block-uniform
    if (bl == 0.0f) {                          // ~30% of tiles: pure zero-fill
        #pragma unroll
        for (int s = 0; s < NSLOT; ++s) {
            const int idx = s * BLK + tid;
            if (s < NSLOT - 1 || idx < NPIX) outp[idx] = 0.0f;
        }
        return;                                // whole block exits before barrier
    }

    const float* p = lens_params + tile * NPARAM;   // uniform -> s_load
    // ---- per-tile params, all fast intrinsics (block-uniform values) ----
    const float flux = __builtin_fmaf(p[0], 1000.0f, 100.0f);
    const float sg   = __builtin_fmaf(p[3], 3.0f, 1.0f);
    const float s2   = sg * sg;
    const float rs2  = __builtin_amdgcn_rcpf(s2);
    const float A    = flux * 0.15915494309189533577f * rs2;  // flux/(2*pi*s2)
    const float nh2  = -0.72134752044448170368f * rs2;        // -0.5*log2(e)/s2
    const float b  = p[7], e1 = p[10], e2 = p[11];
    const float cx26 = p[8] + 26.0f, cy26 = p[9] + 26.0f;     // shifted centers
    const float rell = __builtin_amdgcn_rsqf(__builtin_fmaf(e1, e1, e2 * e2));
    const float cosp = e1 * rell;              // cos(atan(e2/e1)), e1>0
    const float sinp = e2 * rell;
    const float ell  = __builtin_fmaf(e1, cosp, e2 * sinp);   // = sqrt(e1^2+e2^2)
    const float q    = (1.0f - ell) * __builtin_amdgcn_rcpf(1.0f + ell);
    const float qinv = __builtin_amdgcn_rcpf(q);
    const float qf   = __builtin_amdgcn_sqrtf(qinv - q);
    const float safe = fmaxf(qf, 0.001f);
    const float bos  = b * __builtin_amdgcn_rcpf(safe);
    const bool  mb   = (qf >= 0.001f);         // always true for this data

    // ---- per-tile Gaussian corner table (53 exp2 total) ----
    const float sA = __builtin_amdgcn_sqrtf(A * bl);   // bl == 1 here
    if (tid < SLEN) {
        const float d = (float)tid - 26.0f;
        Etab[tid] = sA * __builtin_amdgcn_exp2f((nh2 * d) * d);
    }
    __syncthreads();

    #pragma unroll
    for (int s = 0; s < NSLOT; ++s) {
        int idx = s * BLK + tid;
        if (s == NSLOT - 1) idx = min(idx, NPIX - 1);  // tail: redundant same-value store
        const unsigned i = ((unsigned)idx * 39569u) >> 21;   // idx/53 exact
        const int j = idx - (int)i * 53;
        // shifted coords: xc26 = xc + 26 = j*KC - 1 (exact same float math shape)
        const float xc26 = __builtin_fmaf((float)j, KC, -1.0f);
        const float yc26 = __builtin_fmaf((float)i, KC, -1.0f);

        // ---- SIE deflection ----
        const float dx = xc26 - cx26, dy = yc26 - cy26;
        const float xsie = __builtin_fmaf(dx, cosp, dy * sinp);
        const float ysie = __builtin_fmaf(dy, cosp, -dx * sinp);
        const float arg  = __builtin_fmaf(q * xsie, xsie,
                           __builtin_fmaf(qinv * ysie, ysie, 1e-12f));
        const float rcp_r = __builtin_amdgcn_rsqf(arg);      // 1/r_ell
        float xtg, ytg;
        if (mb) {
            const float srr = safe * rcp_r;                  // hoisted common factor
            xtg = bos * fast_atan(srr * xsie);
            ytg = bos * fast_atanh(srr * ysie);
        } else {
            const float brr = b * rcp_r;
            xtg = brr * xsie;
            ytg = brr * ysie;
        }
        const float xg = __builtin_fmaf(xtg, cosp, -ytg * sinp);
        const float yg = __builtin_fmaf(ytg, cosp,  xtg * sinp);

        // ---- bilinear sample coords ----
        const float xs = xc26 - xg;
        const float ys = yc26 - yg;
        const float fx = __builtin_floorf(xs);
        const float fy = __builtin_floorf(ys);
        const float x0f = fminf(fmaxf(fx,        0.0f), 52.0f);  // v_med3
        const float x1f = fminf(fmaxf(fx + 1.0f, 0.0f), 52.0f);
        const float y0f = fminf(fmaxf(fy,        0.0f), 52.0f);
        const float y1f = fminf(fmaxf(fy + 1.0f, 0.0f), 52.0f);

        // ---- corner Gaussian values from the LDS table ----
        const float Ex0 = Etab[(int)x0f];
        const float Ex1 = Etab[(int)x1f];
        const float Ey0 = Etab[(int)y0f];
        const float Ey1 = Etab[(int)y1f];

        // separable bilinear; sqrt(A*bl) folded into table -> no final scale
        const float Fx = __builtin_fmaf(x1f - xs, Ex0, (xs - x0f) * Ex1);
        const float Fy = __builtin_fmaf(y1f - ys, Ey0, (ys - y0f) * Ey1);
        outp[idx] = Fx * Fy;
    }
}

extern "C" void kernel_launch(void* const* d_in, const int* in_sizes, int n_in,
                              void* d_out, int out_size, void* d_ws, size_t ws_size,
                              hipStream_t stream) {
    const float* lens  = (const float*)d_in[0];  // (N, 1, 12) fp32
    const float* bools = (const float*)d_in[1];  // (N, 1, 1)  fp32
    float* out = (float*)d_out;                  // (N, 1, 1, 53, 53) fp32
    const int n_tiles = in_sizes[1];
    lgtd_kernel<<<n_tiles, BLK, 0, stream>>>(lens, bools, out);
}